// Round 8
// baseline (240.516 us; speedup 1.0000x reference)
//
#include <hip/hip_runtime.h>

// IncrementalRobertaSelfAttentionCross: B=4, Sq=1024, Skv=2048 (enc||dec), D=1024, H=16, HD=64
// Pipeline: Wt transpose + A cast -> QKV GEMM (f16 MFMA, V writes V^T directly)
//           -> flash attn kv-split x2: LDS-free, barrier-free, direct global->reg MFMA frags,
//              XCD-bijective block remap -> merge.

typedef _Float16 f16;
typedef __attribute__((ext_vector_type(4))) _Float16 half4;
typedef __attribute__((ext_vector_type(8))) _Float16 half8;
typedef __attribute__((ext_vector_type(4))) float floatx4;
typedef __attribute__((ext_vector_type(16))) float floatx16;
typedef __attribute__((ext_vector_type(4))) unsigned int uint4v;

#define OPSTRIDE ((size_t)4194304)   // 64bh*1024q*64d elements per kv-split

// ---------------------------------------------------------------- W transpose
__global__ void wt_kernel(const float* __restrict__ W, f16* __restrict__ Wt) {
    __shared__ float tile[32][33];
    int k0 = blockIdx.y * 32, n0 = blockIdx.x * 32;
    int tx = threadIdx.x, ty = threadIdx.y;   // block (32,8)
    #pragma unroll
    for (int i = 0; i < 32; i += 8)
        tile[ty + i][tx] = W[(k0 + ty + i) * 1024 + n0 + tx];
    __syncthreads();
    #pragma unroll
    for (int i = 0; i < 32; i += 8)
        Wt[(n0 + ty + i) * 1024 + k0 + tx] = (f16)tile[tx][ty + i];
}

// ---------------------------------------------------------------- A cast
__global__ void cvt_kernel(const float* __restrict__ hid, const float* __restrict__ enc,
                           f16* __restrict__ Aall) {
    int t = blockIdx.x * 256 + threadIdx.x;
    int rowg = t >> 7, col = (t & 127) * 8;
    int b = rowg >> 11, r = rowg & 2047;
    const float* src = (r < 1024 ? enc + ((size_t)b * 1024 + r) * 1024
                                 : hid + ((size_t)b * 1024 + (r - 1024)) * 1024) + col;
    float4 v0 = *(const float4*)src, v1 = *(const float4*)(src + 4);
    half8 o;
    o[0] = (f16)v0.x; o[1] = (f16)v0.y; o[2] = (f16)v0.z; o[3] = (f16)v0.w;
    o[4] = (f16)v1.x; o[5] = (f16)v1.y; o[6] = (f16)v1.z; o[7] = (f16)v1.w;
    *(half8*)(Aall + (size_t)rowg * 1024 + col) = o;
}

// ---------------------------------------------------------------- mask scale
__global__ void maskscale_kernel(const float* __restrict__ mask, float* __restrict__ maskS) {
    const float LOG2E = 1.4426950408889634f;
    int i = blockIdx.x * 256 + threadIdx.x;   // 2048 float4 = 8192 floats
    float4 v = ((const float4*)mask)[i];
    v.x *= LOG2E; v.y *= LOG2E; v.z *= LOG2E; v.w *= LOG2E;
    ((float4*)maskS)[i] = v;
}

// ---------------------------------------------------------------- QKV GEMM (f16 A)
// mode 0: Q -> [bh][s][64];  mode 1: K -> [bh][s][64];  mode 2: V -> [bh][d][s] (V^T)
__launch_bounds__(256)
__global__ void qkv_gemm(const f16* __restrict__ Aall, const f16* __restrict__ Wt,
                         const float* __restrict__ bias, f16* __restrict__ out, int mode) {
    __shared__ f16 At[128 * 40];
    __shared__ f16 Bt[128 * 40];

    int tid = threadIdx.x;
    int m0 = blockIdx.x * 128, n0 = blockIdx.y * 128;
    int wid = tid >> 6, lane = tid & 63;
    int wm = (wid >> 1) * 64, wn = (wid & 1) * 64;
    int lr = lane & 15, lg = lane >> 4;

    floatx4 acc[4][4];
    #pragma unroll
    for (int i = 0; i < 4; i++)
        #pragma unroll
        for (int j = 0; j < 4; j++) acc[i][j] = (floatx4)(0.f);

    int tr2 = tid >> 2, tk2 = (tid & 3) * 8;
    const f16 *a0src, *a1src;
    {
        int mA0 = m0 + tr2, mA1 = mA0 + 64;
        if (mode == 0) {
            int b0 = mA0 >> 10, b1 = mA1 >> 10;
            a0src = Aall + ((size_t)(b0 * 2048 + 1024 + (mA0 & 1023))) * 1024 + tk2;
            a1src = Aall + ((size_t)(b1 * 2048 + 1024 + (mA1 & 1023))) * 1024 + tk2;
        } else {
            a0src = Aall + (size_t)mA0 * 1024 + tk2;
            a1src = Aall + (size_t)mA1 * 1024 + tk2;
        }
    }
    const f16* b0src = Wt + (size_t)(n0 + tr2) * 1024 + tk2;
    const f16* b1src = Wt + (size_t)(n0 + tr2 + 64) * 1024 + tk2;

    half8 ra0 = *(const half8*)a0src, ra1 = *(const half8*)a1src;
    half8 rb0 = *(const half8*)b0src, rb1 = *(const half8*)b1src;

    for (int k0 = 0; k0 < 1024; k0 += 32) {
        __syncthreads();
        *(half8*)&At[tr2 * 40 + tk2]        = ra0;
        *(half8*)&At[(tr2 + 64) * 40 + tk2] = ra1;
        *(half8*)&Bt[tr2 * 40 + tk2]        = rb0;
        *(half8*)&Bt[(tr2 + 64) * 40 + tk2] = rb1;
        __syncthreads();
        if (k0 < 992) {
            ra0 = *(const half8*)(a0src + k0 + 32);
            ra1 = *(const half8*)(a1src + k0 + 32);
            rb0 = *(const half8*)(b0src + k0 + 32);
            rb1 = *(const half8*)(b1src + k0 + 32);
        }

        half8 a[4], bf[4];
        #pragma unroll
        for (int i = 0; i < 4; i++)
            a[i] = *(const half8*)&At[(wm + i * 16 + lr) * 40 + lg * 8];
        #pragma unroll
        for (int j = 0; j < 4; j++)
            bf[j] = *(const half8*)&Bt[(wn + j * 16 + lr) * 40 + lg * 8];
        __builtin_amdgcn_s_setprio(1);
        #pragma unroll
        for (int i = 0; i < 4; i++)
            #pragma unroll
            for (int j = 0; j < 4; j++)
                acc[i][j] = __builtin_amdgcn_mfma_f32_16x16x32_f16(a[i], bf[j], acc[i][j], 0, 0, 0);
        __builtin_amdgcn_s_setprio(0);
    }

    if (mode == 2) {
        #pragma unroll
        for (int i = 0; i < 4; i++) {
            int mbase = m0 + wm + i * 16 + lg * 4;
            int b = mbase >> 11, s = mbase & 2047;
            #pragma unroll
            for (int j = 0; j < 4; j++) {
                int n = n0 + wn + j * 16 + lr;
                int h = n >> 6, d = n & 63;
                float bv = bias[n];
                half4 w;
                #pragma unroll
                for (int r = 0; r < 4; r++) w[r] = (f16)(acc[i][j][r] + bv);
                *(half4*)(out + ((size_t)((b * 16 + h) * 64 + d)) * 2048 + s) = w;
            }
        }
    } else {
        int Sout = (mode == 0) ? 1024 : 2048;
        #pragma unroll
        for (int i = 0; i < 4; i++) {
            int mbase = m0 + wm + i * 16 + lg * 4;
            #pragma unroll
            for (int j = 0; j < 4; j++) {
                int n = n0 + wn + j * 16 + lr;
                int h = n >> 6, d = n & 63;
                float bv = bias[n];
                #pragma unroll
                for (int r = 0; r < 4; r++) {
                    int m = mbase + r;
                    int b = (mode == 0) ? (m >> 10) : (m >> 11);
                    int s = (mode == 0) ? (m & 1023) : (m & 2047);
                    out[((size_t)(b * 16 + h) * Sout + s) * 64 + d] = (f16)(acc[i][j][r] + bv);
                }
            }
        }
    }
}

// ---------------------------------------------------------------- flash attention (kv-split, LDS-free)
__device__ inline half8 pack_swap(float s0, float s1, float s2, float s3,
                                  float s4, float s5, float s6, float s7) {
    unsigned a0 = __builtin_bit_cast(unsigned, __builtin_amdgcn_cvt_pkrtz(s0, s1));
    unsigned b0 = __builtin_bit_cast(unsigned, __builtin_amdgcn_cvt_pkrtz(s4, s5));
    unsigned a1 = __builtin_bit_cast(unsigned, __builtin_amdgcn_cvt_pkrtz(s2, s3));
    unsigned b1 = __builtin_bit_cast(unsigned, __builtin_amdgcn_cvt_pkrtz(s6, s7));
    asm("v_permlane32_swap_b32 %0, %1" : "+v"(a0), "+v"(b0));
    asm("v_permlane32_swap_b32 %0, %1" : "+v"(a1), "+v"(b1));
    uint4v w = {a0, a1, b0, b1};
    return __builtin_bit_cast(half8, w);
}

__device__ inline half8 pack_noswap(float s0, float s1, float s2, float s3,
                                    float s4, float s5, float s6, float s7) {
    unsigned w0 = __builtin_bit_cast(unsigned, __builtin_amdgcn_cvt_pkrtz(s0, s1));
    unsigned w1 = __builtin_bit_cast(unsigned, __builtin_amdgcn_cvt_pkrtz(s2, s3));
    unsigned w2 = __builtin_bit_cast(unsigned, __builtin_amdgcn_cvt_pkrtz(s4, s5));
    unsigned w3 = __builtin_bit_cast(unsigned, __builtin_amdgcn_cvt_pkrtz(s6, s7));
    uint4v w = {w0, w1, w2, w3};
    return __builtin_bit_cast(half8, w);
}

struct F4x4 { float4 a, b, c, d; };

// Q [bh][1024][64], K [bh][2048][64], Vt [bh][64][2048] f16, maskS [B][2048] f32 (pre *log2e).
// No LDS, no barriers: K/V/mask load straight into MFMA fragments. Writes unnormalized O + (m,l).
__launch_bounds__(256, 3)
__global__ void attn_kernel(const f16* __restrict__ Q, const f16* __restrict__ K,
                            const f16* __restrict__ Vt, const float* __restrict__ maskS,
                            f16* __restrict__ Opart, float* __restrict__ mlbuf) {
    int tid = threadIdx.x;
    int wid = tid >> 6, lane = tid & 63;
    int l31 = lane & 31, l5 = lane >> 5;

    // XCD-bijective remap: all 8 q-blocks of one (bh,sp) land on one XCD (16 pairs/XCD = 4MB K/V = L2)
    int bid = blockIdx.x + 8 * blockIdx.y + 512 * blockIdx.z;   // grid (8,64,2)
    int xcd = bid & 7, w = bid >> 3;
    int pair = xcd * 16 + (w >> 3);
    int xblk = w & 7;
    int sp = pair & 1, bh = pair >> 1;
    int b = bh >> 4;
    int q = xblk * 128 + wid * 32 + l31;

    // runtime probe of the 32x32x16 B-operand k-layout (flat vs two-block)
    half8 pa, pcode;
    #pragma unroll
    for (int j = 0; j < 8; j++) { pa[j] = (f16)0; pcode[j] = (f16)(8 * l5 + j); }
    if (l31 < 16 && (l31 >> 3) == l5) pa[l31 & 7] = (f16)1;
    floatx16 pd = __builtin_amdgcn_mfma_f32_32x32x16_f16(pa, pcode, (floatx16)0.f, 0, 0, 0);
    float r4 = __shfl(pd[0], 32);
    bool twoblk = (r4 > 6.0f);

    // Q frags pre-scaled by 0.125*log2e, per probed B k-map
    const f16* qrow = Q + ((size_t)bh * 1024 + q) * 64;
    half8 qf[4];
    if (!twoblk) {
        #pragma unroll
        for (int ks = 0; ks < 4; ks++)
            qf[ks] = *(const half8*)(qrow + ks * 16 + l5 * 8);
    } else {
        #pragma unroll
        for (int ks = 0; ks < 4; ks++) {
            half4 lo = *(const half4*)(qrow + ks * 16 + 4 * l5);
            half4 hi = *(const half4*)(qrow + ks * 16 + 8 + 4 * l5);
            qf[ks][0] = lo[0]; qf[ks][1] = lo[1]; qf[ks][2] = lo[2]; qf[ks][3] = lo[3];
            qf[ks][4] = hi[0]; qf[ks][5] = hi[1]; qf[ks][6] = hi[2]; qf[ks][7] = hi[3];
        }
    }
    const f16 qs = (f16)(0.125f * 1.4426950408889634f);
    #pragma unroll
    for (int ks = 0; ks < 4; ks++)
        #pragma unroll
        for (int x = 0; x < 8; x++) qf[ks][x] *= qs;

    floatx16 o0 = (floatx16)0.f, o1 = (floatx16)0.f;
    float m_run = -1e30f, l_run = 0.f;

    // per-lane fragment base pointers (A-operand layout == row-major global layout)
    const f16* Kb = K + ((size_t)(bh * 2048 + sp * 1024 + l31)) * 64 + l5 * 8;   // row kv, col d
    const f16* Vb = Vt + ((size_t)(bh * 64 + l31)) * 2048 + sp * 1024 + l5 * 8;  // row d, col kv
    const float* Mb = maskS + b * 2048 + sp * 1024 + 4 * l5;

    // prologue: K/V frags for tile 0 (in-place rotation thereafter)
    half8 kf[2][4], vf[2][4];
    #pragma unroll
    for (int ih = 0; ih < 2; ih++)
        #pragma unroll
        for (int ks = 0; ks < 4; ks++)
            kf[ih][ks] = *(const half8*)(Kb + (ih * 32) * 64 + ks * 16);
    #pragma unroll
    for (int ih = 0; ih < 2; ih++)
        #pragma unroll
        for (int kb = 0; kb < 4; kb++)
            vf[ih][kb] = *(const half8*)(Vb + (ih * 32) * 2048 + kb * 16);

    for (int kv0 = 0; kv0 < 1024; kv0 += 64) {
        // S init = mask (log2 domain), loaded straight into the MFMA C-input (L1-resident)
        F4x4 t0, t1;
        t0.a = *(const float4*)(Mb + kv0);      t0.b = *(const float4*)(Mb + kv0 + 8);
        t0.c = *(const float4*)(Mb + kv0 + 16); t0.d = *(const float4*)(Mb + kv0 + 24);
        t1.a = *(const float4*)(Mb + kv0 + 32); t1.b = *(const float4*)(Mb + kv0 + 40);
        t1.c = *(const float4*)(Mb + kv0 + 48); t1.d = *(const float4*)(Mb + kv0 + 56);
        floatx16 sf0 = __builtin_bit_cast(floatx16, t0);
        floatx16 sf1 = __builtin_bit_cast(floatx16, t1);

        // QK^T (swapped): A = K rows from registers, B = Q
        __builtin_amdgcn_s_setprio(1);
        #pragma unroll
        for (int ks = 0; ks < 4; ks++) {
            sf0 = __builtin_amdgcn_mfma_f32_32x32x16_f16(kf[0][ks], qf[ks], sf0, 0, 0, 0);
            sf1 = __builtin_amdgcn_mfma_f32_32x32x16_f16(kf[1][ks], qf[ks], sf1, 0, 0, 0);
        }
        __builtin_amdgcn_s_setprio(0);

        // rotate K frags: prefetch next tile into the just-consumed registers
        if (kv0 < 1024 - 64) {
            #pragma unroll
            for (int ih = 0; ih < 2; ih++)
                #pragma unroll
                for (int ks = 0; ks < 4; ks++)
                    kf[ih][ks] = *(const half8*)(Kb + (size_t)(kv0 + 64 + ih * 32) * 64 + ks * 16);
        }

        float pmax = -1e30f;
        #pragma unroll
        for (int r = 0; r < 16; r++)
            pmax = fmaxf(pmax, fmaxf(sf0[r], sf1[r]));

        if (!__all(pmax - m_run <= 8.0f)) {
            float rmax = fmaxf(pmax, __shfl_xor(pmax, 32));
            float mnew = fmaxf(m_run, rmax);
            float alpha = exp2f(m_run - mnew);
            l_run *= alpha;
            #pragma unroll
            for (int r = 0; r < 16; r++) { o0[r] *= alpha; o1[r] *= alpha; }
            m_run = mnew;
        }

        float ls = 0.f;
        #pragma unroll
        for (int r = 0; r < 16; r++) {
            float p0 = exp2f(sf0[r] - m_run);
            float p1 = exp2f(sf1[r] - m_run);
            sf0[r] = p0; sf1[r] = p1;
            ls += p0 + p1;
        }
        ls += __shfl_xor(ls, 32);
        l_run += ls;

        half8 pb[4];
        if (!twoblk) {
            pb[0] = pack_swap(sf0[0], sf0[1], sf0[2], sf0[3], sf0[4], sf0[5], sf0[6], sf0[7]);
            pb[1] = pack_swap(sf0[8], sf0[9], sf0[10], sf0[11], sf0[12], sf0[13], sf0[14], sf0[15]);
            pb[2] = pack_swap(sf1[0], sf1[1], sf1[2], sf1[3], sf1[4], sf1[5], sf1[6], sf1[7]);
            pb[3] = pack_swap(sf1[8], sf1[9], sf1[10], sf1[11], sf1[12], sf1[13], sf1[14], sf1[15]);
        } else {
            pb[0] = pack_noswap(sf0[0], sf0[1], sf0[2], sf0[3], sf0[4], sf0[5], sf0[6], sf0[7]);
            pb[1] = pack_noswap(sf0[8], sf0[9], sf0[10], sf0[11], sf0[12], sf0[13], sf0[14], sf0[15]);
            pb[2] = pack_noswap(sf1[0], sf1[1], sf1[2], sf1[3], sf1[4], sf1[5], sf1[6], sf1[7]);
            pb[3] = pack_noswap(sf1[8], sf1[9], sf1[10], sf1[11], sf1[12], sf1[13], sf1[14], sf1[15]);
        }

        // PV (swapped): O^T[d][q] += V^T[d][kv] P^T[kv][q]
        __builtin_amdgcn_s_setprio(1);
        #pragma unroll
        for (int kb = 0; kb < 4; kb++) {
            o0 = __builtin_amdgcn_mfma_f32_32x32x16_f16(vf[0][kb], pb[kb], o0, 0, 0, 0);
            o1 = __builtin_amdgcn_mfma_f32_32x32x16_f16(vf[1][kb], pb[kb], o1, 0, 0, 0);
        }
        __builtin_amdgcn_s_setprio(0);

        // rotate V frags
        if (kv0 < 1024 - 64) {
            #pragma unroll
            for (int ih = 0; ih < 2; ih++)
                #pragma unroll
                for (int kb = 0; kb < 4; kb++)
                    vf[ih][kb] = *(const half8*)(Vb + (size_t)(ih * 32) * 2048 + kv0 + 64 + kb * 16);
        }
    }

    // epilogue: unnormalized O -> f16 partials, (m,l) -> f32
    size_t row = (size_t)bh * 1024 + q;
    size_t obase = (size_t)sp * OPSTRIDE + row * 64;
    #pragma unroll
    for (int g = 0; g < 4; g++) {
        half4 w0, w1;
        #pragma unroll
        for (int r = 0; r < 4; r++) {
            w0[r] = (f16)o0[4 * g + r];
            w1[r] = (f16)o1[4 * g + r];
        }
        *(half4*)(Opart + obase + 8 * g + 4 * l5)      = w0;
        *(half4*)(Opart + obase + 32 + 8 * g + 4 * l5) = w1;
    }
    if (l5 == 0) {
        float2 v = {m_run, l_run};
        *(float2*)(mlbuf + ((size_t)sp * 65536 + row) * 2) = v;
    }
}

// ---------------------------------------------------------------- merge
__global__ void merge_kernel(const f16* __restrict__ Op, const float* __restrict__ ml,
                             float* __restrict__ out) {
    int t = blockIdx.x * 256 + threadIdx.x;   // 65536 rows x 8 chunks
    int row = t >> 3, dc = (t & 7) * 8;
    int bh = row >> 10, q = row & 1023, b = bh >> 4, h = bh & 15;
    float2 ml0 = *(const float2*)(ml + (size_t)row * 2);
    float2 ml1 = *(const float2*)(ml + ((size_t)65536 + row) * 2);
    float mm = fmaxf(ml0.x, ml1.x);
    float w0 = exp2f(ml0.x - mm), w1 = exp2f(ml1.x - mm);
    float inv = 1.f / (ml0.y * w0 + ml1.y * w1);
    w0 *= inv; w1 *= inv;
    half8 a = *(const half8*)(Op + (size_t)row * 64 + dc);
    half8 c = *(const half8*)(Op + OPSTRIDE + (size_t)row * 64 + dc);
    float* orow = out + ((size_t)(b * 1024 + q)) * 1024 + h * 64 + dc;
    float4 lo = {(float)a[0] * w0 + (float)c[0] * w1, (float)a[1] * w0 + (float)c[1] * w1,
                 (float)a[2] * w0 + (float)c[2] * w1, (float)a[3] * w0 + (float)c[3] * w1};
    float4 hi = {(float)a[4] * w0 + (float)c[4] * w1, (float)a[5] * w0 + (float)c[5] * w1,
                 (float)a[6] * w0 + (float)c[6] * w1, (float)a[7] * w0 + (float)c[7] * w1};
    *(float4*)orow = lo;
    *(float4*)(orow + 4) = hi;
}

// ---------------------------------------------------------------- launcher
extern "C" void kernel_launch(void* const* d_in, const int* in_sizes, int n_in,
                              void* d_out, int out_size, void* d_ws, size_t ws_size,
                              hipStream_t stream) {
    const float* hid  = (const float*)d_in[0];
    const float* enc  = (const float*)d_in[1];
    const float* mask = (const float*)d_in[2];
    const float* Wq   = (const float*)d_in[3];
    const float* bq   = (const float*)d_in[4];
    const float* Wk   = (const float*)d_in[5];
    const float* bk   = (const float*)d_in[6];
    const float* Wv   = (const float*)d_in[7];
    const float* bv   = (const float*)d_in[8];
    float* out = (float*)d_out;

    char* ws = (char*)d_ws;
    // Phase-1 buffers (dead once attn starts):
    f16* Wtq  = (f16*)(ws + ((size_t)0 << 20));
    f16* Wtk  = (f16*)(ws + ((size_t)2 << 20));
    f16* Wtv  = (f16*)(ws + ((size_t)4 << 20));
    f16* Aall = (f16*)(ws + ((size_t)6 << 20));   // 16 MiB
    // Phase-2 buffers:
    f16* Qw   = (f16*)(ws + ((size_t)22 << 20));  // 8 MiB
    f16* Kw   = (f16*)(ws + ((size_t)30 << 20));  // 16 MiB
    f16* Vtw  = (f16*)(ws + ((size_t)46 << 20));  // 16 MiB
    // Attn-phase overlays on the dead phase-1 region (stream-ordered):
    f16*   Opart = (f16*)(ws + ((size_t)0 << 20));    // 2 x 8 MiB
    float* mlbuf = (float*)(ws + ((size_t)17 << 20)); // 1 MiB
    float* maskS = (float*)(ws + ((size_t)18 << 20)); // 32 KiB (written AFTER gemms, Aall dead)

    dim3 tb(32, 8);
    wt_kernel<<<dim3(32, 32), tb, 0, stream>>>(Wq, Wtq);
    wt_kernel<<<dim3(32, 32), tb, 0, stream>>>(Wk, Wtk);
    wt_kernel<<<dim3(32, 32), tb, 0, stream>>>(Wv, Wtv);
    cvt_kernel<<<4096, 256, 0, stream>>>(hid, enc, Aall);

    qkv_gemm<<<dim3(32, 8), 256, 0, stream>>>(Aall, Wtq, bq, Qw, 0);
    qkv_gemm<<<dim3(64, 8), 256, 0, stream>>>(Aall, Wtk, bk, Kw, 1);
    qkv_gemm<<<dim3(64, 8), 256, 0, stream>>>(Aall, Wtv, bv, Vtw, 2);

    maskscale_kernel<<<8, 256, 0, stream>>>(mask, maskS);
    attn_kernel<<<dim3(8, 64, 2), 256, 0, stream>>>(Qw, Kw, Vtw, maskS, Opart, mlbuf);
    merge_kernel<<<2048, 256, 0, stream>>>(Opart, mlbuf, out);
}

// Round 9
// 174.404 us; speedup vs baseline: 1.3791x; 1.3791x over previous
//
#include <hip/hip_runtime.h>

// IncrementalRobertaSelfAttentionCross: B=4, Sq=1024, Skv=2048 (enc||dec), D=1024, H=16, HD=64
// Pipeline: Wt transpose (z-fused) + A cast -> QKV GEMM (m97-style global_load_lds staging)
//           -> flash attn (round-6 LDS-staged, global mask C-init, XCD-bijective remap).

typedef _Float16 f16;
typedef __attribute__((ext_vector_type(4))) _Float16 half4;
typedef __attribute__((ext_vector_type(8))) _Float16 half8;
typedef __attribute__((ext_vector_type(4))) float floatx4;
typedef __attribute__((ext_vector_type(16))) float floatx16;
typedef __attribute__((ext_vector_type(4))) unsigned int uint4v;

#define GLOAD16(gp, lp)                                                        \
    __builtin_amdgcn_global_load_lds(                                          \
        (const __attribute__((address_space(1))) void*)(gp),                   \
        (__attribute__((address_space(3))) void*)(lp), 16, 0, 0)

// ---------------------------------------------------------------- W transpose (all 3 via z)
__global__ void wt_kernel(const float* __restrict__ Wq, const float* __restrict__ Wk,
                          const float* __restrict__ Wv, f16* __restrict__ Wtq,
                          f16* __restrict__ Wtk, f16* __restrict__ Wtv) {
    __shared__ float tile[32][33];
    const float* W = (blockIdx.z == 0) ? Wq : (blockIdx.z == 1) ? Wk : Wv;
    f16* Wt = (blockIdx.z == 0) ? Wtq : (blockIdx.z == 1) ? Wtk : Wtv;
    int k0 = blockIdx.y * 32, n0 = blockIdx.x * 32;
    int tx = threadIdx.x, ty = threadIdx.y;   // block (32,8)
    #pragma unroll
    for (int i = 0; i < 32; i += 8)
        tile[ty + i][tx] = W[(k0 + ty + i) * 1024 + n0 + tx];
    __syncthreads();
    #pragma unroll
    for (int i = 0; i < 32; i += 8)
        Wt[(n0 + ty + i) * 1024 + k0 + tx] = (f16)tile[tx][ty + i];
}

// ---------------------------------------------------------------- A cast
__global__ void cvt_kernel(const float* __restrict__ hid, const float* __restrict__ enc,
                           f16* __restrict__ Aall) {
    int t = blockIdx.x * 256 + threadIdx.x;
    int rowg = t >> 7, col = (t & 127) * 8;
    int b = rowg >> 11, r = rowg & 2047;
    const float* src = (r < 1024 ? enc + ((size_t)b * 1024 + r) * 1024
                                 : hid + ((size_t)b * 1024 + (r - 1024)) * 1024) + col;
    float4 v0 = *(const float4*)src, v1 = *(const float4*)(src + 4);
    half8 o;
    o[0] = (f16)v0.x; o[1] = (f16)v0.y; o[2] = (f16)v0.z; o[3] = (f16)v0.w;
    o[4] = (f16)v1.x; o[5] = (f16)v1.y; o[6] = (f16)v1.z; o[7] = (f16)v1.w;
    *(half8*)(Aall + (size_t)rowg * 1024 + col) = o;
}

// ---------------------------------------------------------------- mask scale (*log2e)
__global__ void maskscale_kernel(const float* __restrict__ mask, float* __restrict__ maskS) {
    const float LOG2E = 1.4426950408889634f;
    int i = blockIdx.x * 256 + threadIdx.x;   // 2048 float4 = 8192 floats
    float4 v = ((const float4*)mask)[i];
    v.x *= LOG2E; v.y *= LOG2E; v.z *= LOG2E; v.w *= LOG2E;
    ((float4*)maskS)[i] = v;
}

// ---------------------------------------------------------------- QKV GEMM (m97-style staging)
// mode 0: Q -> [bh][s][64];  mode 1: K -> [bh][s][64];  mode 2: V -> [bh][d][s] (V^T)
__launch_bounds__(256)
__global__ void qkv_gemm(const f16* __restrict__ Aall, const f16* __restrict__ Wt,
                         const float* __restrict__ bias, f16* __restrict__ out, int mode) {
    __shared__ f16 As[128 * 32];   // [row][k32] linear (global_load_lds dest)
    __shared__ f16 Bs[128 * 32];

    int tid = threadIdx.x;
    int m0 = blockIdx.x * 128, n0 = blockIdx.y * 128;
    int wid = tid >> 6, lane = tid & 63;
    int wm = (wid >> 1) * 64, wn = (wid & 1) * 64;
    int lr = lane & 15, lg = lane >> 4;

    floatx4 acc[4][4];
    #pragma unroll
    for (int i = 0; i < 4; i++)
        #pragma unroll
        for (int j = 0; j < 4; j++) acc[i][j] = (floatx4)(0.f);

    // staging: thread t covers rows (t>>2) and (t>>2)+64, 16B col chunk (t&3)
    int trow = tid >> 2, tcol = (tid & 3) * 8;
    const f16 *a0g, *a1g;
    {
        int mA0 = m0 + trow, mA1 = mA0 + 64;
        if (mode == 0) {
            int b0 = mA0 >> 10, b1 = mA1 >> 10;
            a0g = Aall + ((size_t)(b0 * 2048 + 1024 + (mA0 & 1023))) * 1024 + tcol;
            a1g = Aall + ((size_t)(b1 * 2048 + 1024 + (mA1 & 1023))) * 1024 + tcol;
        } else {
            a0g = Aall + (size_t)mA0 * 1024 + tcol;
            a1g = Aall + (size_t)mA1 * 1024 + tcol;
        }
    }
    const f16* b0g = Wt + (size_t)(n0 + trow) * 1024 + tcol;
    const f16* b1g = Wt + (size_t)(n0 + trow + 64) * 1024 + tcol;
    f16* lA0 = &As[tid * 8];          // byte offset tid*16
    f16* lA1 = &As[tid * 8 + 2048];   // +4096 bytes
    f16* lB0 = &Bs[tid * 8];
    f16* lB1 = &Bs[tid * 8 + 2048];

    for (int k0 = 0; k0 < 1024; k0 += 32) {
        GLOAD16(a0g + k0, lA0);
        GLOAD16(a1g + k0, lA1);
        GLOAD16(b0g + k0, lB0);
        GLOAD16(b1g + k0, lB1);
        __syncthreads();   // drains vmcnt (compiler-inserted) - tile ready

        half8 a[4], bf[4];
        #pragma unroll
        for (int i = 0; i < 4; i++)
            a[i] = *(const half8*)&As[(wm + i * 16 + lr) * 32 + lg * 8];
        #pragma unroll
        for (int j = 0; j < 4; j++)
            bf[j] = *(const half8*)&Bs[(wn + j * 16 + lr) * 32 + lg * 8];
        __builtin_amdgcn_s_setprio(1);
        #pragma unroll
        for (int i = 0; i < 4; i++)
            #pragma unroll
            for (int j = 0; j < 4; j++)
                acc[i][j] = __builtin_amdgcn_mfma_f32_16x16x32_f16(a[i], bf[j], acc[i][j], 0, 0, 0);
        __builtin_amdgcn_s_setprio(0);
        __syncthreads();   // tile consumed
    }

    if (mode == 2) {
        #pragma unroll
        for (int i = 0; i < 4; i++) {
            int mbase = m0 + wm + i * 16 + lg * 4;
            int b = mbase >> 11, s = mbase & 2047;
            #pragma unroll
            for (int j = 0; j < 4; j++) {
                int n = n0 + wn + j * 16 + lr;
                int h = n >> 6, d = n & 63;
                float bv = bias[n];
                half4 w;
                #pragma unroll
                for (int r = 0; r < 4; r++) w[r] = (f16)(acc[i][j][r] + bv);
                *(half4*)(out + ((size_t)((b * 16 + h) * 64 + d)) * 2048 + s) = w;
            }
        }
    } else {
        int Sout = (mode == 0) ? 1024 : 2048;
        #pragma unroll
        for (int i = 0; i < 4; i++) {
            int mbase = m0 + wm + i * 16 + lg * 4;
            #pragma unroll
            for (int j = 0; j < 4; j++) {
                int n = n0 + wn + j * 16 + lr;
                int h = n >> 6, d = n & 63;
                float bv = bias[n];
                #pragma unroll
                for (int r = 0; r < 4; r++) {
                    int m = mbase + r;
                    int b = (mode == 0) ? (m >> 10) : (m >> 11);
                    int s = (mode == 0) ? (m & 1023) : (m & 2047);
                    out[((size_t)(b * 16 + h) * Sout + s) * 64 + d] = (f16)(acc[i][j][r] + bv);
                }
            }
        }
    }
}

// ---------------------------------------------------------------- flash attention
__device__ inline half8 pack_swap(float s0, float s1, float s2, float s3,
                                  float s4, float s5, float s6, float s7) {
    unsigned a0 = __builtin_bit_cast(unsigned, __builtin_amdgcn_cvt_pkrtz(s0, s1));
    unsigned b0 = __builtin_bit_cast(unsigned, __builtin_amdgcn_cvt_pkrtz(s4, s5));
    unsigned a1 = __builtin_bit_cast(unsigned, __builtin_amdgcn_cvt_pkrtz(s2, s3));
    unsigned b1 = __builtin_bit_cast(unsigned, __builtin_amdgcn_cvt_pkrtz(s6, s7));
    asm("v_permlane32_swap_b32 %0, %1" : "+v"(a0), "+v"(b0));
    asm("v_permlane32_swap_b32 %0, %1" : "+v"(a1), "+v"(b1));
    uint4v w = {a0, a1, b0, b1};
    return __builtin_bit_cast(half8, w);
}

__device__ inline half8 pack_noswap(float s0, float s1, float s2, float s3,
                                    float s4, float s5, float s6, float s7) {
    unsigned w0 = __builtin_bit_cast(unsigned, __builtin_amdgcn_cvt_pkrtz(s0, s1));
    unsigned w1 = __builtin_bit_cast(unsigned, __builtin_amdgcn_cvt_pkrtz(s2, s3));
    unsigned w2 = __builtin_bit_cast(unsigned, __builtin_amdgcn_cvt_pkrtz(s4, s5));
    unsigned w3 = __builtin_bit_cast(unsigned, __builtin_amdgcn_cvt_pkrtz(s6, s7));
    uint4v w = {w0, w1, w2, w3};
    return __builtin_bit_cast(half8, w);
}

struct F4x4 { float4 a, b, c, d; };

// Q [bh][1024][64], K [bh][2048][64], Vt [bh][64][2048] f16, maskS [B][2048] f32 (pre *log2e).
// Round-6 LDS-staged loop; mask loads straight into MFMA C-init; XCD-bijective block remap.
__launch_bounds__(256)
__global__ void attn_kernel(const f16* __restrict__ Q, const f16* __restrict__ K,
                            const f16* __restrict__ Vt, const float* __restrict__ maskS,
                            float* __restrict__ out) {
    __shared__ f16 Kt[64 * 72];
    __shared__ f16 Vtt[64 * 72];

    int tid = threadIdx.x;
    int wid = tid >> 6, lane = tid & 63;
    int l31 = lane & 31, l5 = lane >> 5;

    // XCD-bijective remap (validated r8: FETCH 139->22MB): 8 q-blocks of one bh on one XCD
    int bid = blockIdx.x + 8 * blockIdx.y;   // grid (8,64) = 512
    int xcd = bid & 7, w = bid >> 3;
    int bh = xcd * 8 + (w >> 3);
    int xblk = w & 7;
    int b = bh >> 4;
    int q = xblk * 128 + wid * 32 + l31;

    // runtime probe of the 32x32x16 B-operand k-layout (flat vs two-block)
    half8 pa, pcode;
    #pragma unroll
    for (int j = 0; j < 8; j++) { pa[j] = (f16)0; pcode[j] = (f16)(8 * l5 + j); }
    if (l31 < 16 && (l31 >> 3) == l5) pa[l31 & 7] = (f16)1;
    floatx16 pd = __builtin_amdgcn_mfma_f32_32x32x16_f16(pa, pcode, (floatx16)0.f, 0, 0, 0);
    float r4 = __shfl(pd[0], 32);
    bool twoblk = (r4 > 6.0f);

    // Q frags pre-scaled by 0.125*log2e, per probed B k-map
    const f16* qrow = Q + ((size_t)bh * 1024 + q) * 64;
    half8 qf[4];
    if (!twoblk) {
        #pragma unroll
        for (int ks = 0; ks < 4; ks++)
            qf[ks] = *(const half8*)(qrow + ks * 16 + l5 * 8);
    } else {
        #pragma unroll
        for (int ks = 0; ks < 4; ks++) {
            half4 lo = *(const half4*)(qrow + ks * 16 + 4 * l5);
            half4 hi = *(const half4*)(qrow + ks * 16 + 8 + 4 * l5);
            qf[ks][0] = lo[0]; qf[ks][1] = lo[1]; qf[ks][2] = lo[2]; qf[ks][3] = lo[3];
            qf[ks][4] = hi[0]; qf[ks][5] = hi[1]; qf[ks][6] = hi[2]; qf[ks][7] = hi[3];
        }
    }
    const f16 qs = (f16)(0.125f * 1.4426950408889634f);
    #pragma unroll
    for (int ks = 0; ks < 4; ks++)
        #pragma unroll
        for (int x = 0; x < 8; x++) qf[ks][x] *= qs;

    floatx16 o0 = (floatx16)0.f, o1 = (floatx16)0.f;
    float m_run = 8.0f, l_run = 0.f;   // floor init: first-tile rescale never fires

    int sr = tid >> 2, sc = (tid & 3) * 16;
    const f16* Ksrc = K + ((size_t)bh * 2048 + sr) * 64 + sc;
    const f16* Vsrc = Vt + ((size_t)(bh * 64 + sr)) * 2048 + sc;
    const float* Mb = maskS + b * 2048 + 4 * l5;

    half8 rk0 = *(const half8*)(Ksrc);
    half8 rk1 = *(const half8*)(Ksrc + 8);
    half8 rv0 = *(const half8*)(Vsrc);
    half8 rv1 = *(const half8*)(Vsrc + 8);

    for (int kv0 = 0; kv0 < 2048; kv0 += 64) {
        __syncthreads();
        *(half8*)&Kt[sr * 72 + sc]      = rk0;
        *(half8*)&Kt[sr * 72 + sc + 8]  = rk1;
        *(half8*)&Vtt[sr * 72 + sc]     = rv0;
        *(half8*)&Vtt[sr * 72 + sc + 8] = rv1;
        __syncthreads();
        if (kv0 < 2048 - 64) {
            rk0 = *(const half8*)(Ksrc + (size_t)(kv0 + 64) * 64);
            rk1 = *(const half8*)(Ksrc + (size_t)(kv0 + 64) * 64 + 8);
            rv0 = *(const half8*)(Vsrc + kv0 + 64);
            rv1 = *(const half8*)(Vsrc + kv0 + 64 + 8);
        }

        // S init = mask (log2 domain) loaded straight into C-in (32KB, L2-resident)
        F4x4 t0, t1;
        t0.a = *(const float4*)(Mb + kv0);      t0.b = *(const float4*)(Mb + kv0 + 8);
        t0.c = *(const float4*)(Mb + kv0 + 16); t0.d = *(const float4*)(Mb + kv0 + 24);
        t1.a = *(const float4*)(Mb + kv0 + 32); t1.b = *(const float4*)(Mb + kv0 + 40);
        t1.c = *(const float4*)(Mb + kv0 + 48); t1.d = *(const float4*)(Mb + kv0 + 56);
        floatx16 sf0 = __builtin_bit_cast(floatx16, t0);
        floatx16 sf1 = __builtin_bit_cast(floatx16, t1);

        // QK^T (swapped): A = K rows (flat layout), B = Q (probed layout)
        __builtin_amdgcn_s_setprio(1);
        #pragma unroll
        for (int ks = 0; ks < 4; ks++) {
            half8 k0 = *(const half8*)&Kt[l31 * 72 + ks * 16 + l5 * 8];
            half8 k1 = *(const half8*)&Kt[(32 + l31) * 72 + ks * 16 + l5 * 8];
            sf0 = __builtin_amdgcn_mfma_f32_32x32x16_f16(k0, qf[ks], sf0, 0, 0, 0);
            sf1 = __builtin_amdgcn_mfma_f32_32x32x16_f16(k1, qf[ks], sf1, 0, 0, 0);
        }
        __builtin_amdgcn_s_setprio(0);

        float pmax = -1e30f;
        #pragma unroll
        for (int r = 0; r < 16; r++)
            pmax = fmaxf(pmax, fmaxf(sf0[r], sf1[r]));

        // defer-max rescale (THR=8 in log2 units); with floor init this rarely fires
        if (!__all(pmax - m_run <= 8.0f)) {
            float rmax = fmaxf(pmax, __shfl_xor(pmax, 32));
            float mnew = fmaxf(m_run, rmax);
            float alpha = exp2f(m_run - mnew);
            l_run *= alpha;
            #pragma unroll
            for (int r = 0; r < 16; r++) { o0[r] *= alpha; o1[r] *= alpha; }
            m_run = mnew;
        }

        float ls = 0.f;
        #pragma unroll
        for (int r = 0; r < 16; r++) {
            float p0 = exp2f(sf0[r] - m_run);
            float p1 = exp2f(sf1[r] - m_run);
            sf0[r] = p0; sf1[r] = p1;
            ls += p0 + p1;
        }
        ls += __shfl_xor(ls, 32);
        l_run += ls;

        half8 pb[4];
        if (!twoblk) {
            pb[0] = pack_swap(sf0[0], sf0[1], sf0[2], sf0[3], sf0[4], sf0[5], sf0[6], sf0[7]);
            pb[1] = pack_swap(sf0[8], sf0[9], sf0[10], sf0[11], sf0[12], sf0[13], sf0[14], sf0[15]);
            pb[2] = pack_swap(sf1[0], sf1[1], sf1[2], sf1[3], sf1[4], sf1[5], sf1[6], sf1[7]);
            pb[3] = pack_swap(sf1[8], sf1[9], sf1[10], sf1[11], sf1[12], sf1[13], sf1[14], sf1[15]);
        } else {
            pb[0] = pack_noswap(sf0[0], sf0[1], sf0[2], sf0[3], sf0[4], sf0[5], sf0[6], sf0[7]);
            pb[1] = pack_noswap(sf0[8], sf0[9], sf0[10], sf0[11], sf0[12], sf0[13], sf0[14], sf0[15]);
            pb[2] = pack_noswap(sf1[0], sf1[1], sf1[2], sf1[3], sf1[4], sf1[5], sf1[6], sf1[7]);
            pb[3] = pack_noswap(sf1[8], sf1[9], sf1[10], sf1[11], sf1[12], sf1[13], sf1[14], sf1[15]);
        }

        // PV (swapped): O^T[d][q] += V^T[d][kv] P^T[kv][q]
        __builtin_amdgcn_s_setprio(1);
        #pragma unroll
        for (int kb = 0; kb < 4; kb++) {
            half8 v0 = *(const half8*)&Vtt[l31 * 72 + kb * 16 + l5 * 8];
            half8 v1 = *(const half8*)&Vtt[(32 + l31) * 72 + kb * 16 + l5 * 8];
            o0 = __builtin_amdgcn_mfma_f32_32x32x16_f16(v0, pb[kb], o0, 0, 0, 0);
            o1 = __builtin_amdgcn_mfma_f32_32x32x16_f16(v1, pb[kb], o1, 0, 0, 0);
        }
        __builtin_amdgcn_s_setprio(0);
    }

    // epilogue: o[dt][r] is O^T[d = dt*32 + (r&3)+8*(r>>2)+4*l5][q = l31]
    int h = bh & 15;
    float inv = 1.f / l_run;
    float* orow = out + ((size_t)(b * 1024 + q)) * 1024 + h * 64;
    #pragma unroll
    for (int g = 0; g < 4; g++) {
        float4 r0 = {o0[4 * g] * inv, o0[4 * g + 1] * inv, o0[4 * g + 2] * inv, o0[4 * g + 3] * inv};
        float4 r1 = {o1[4 * g] * inv, o1[4 * g + 1] * inv, o1[4 * g + 2] * inv, o1[4 * g + 3] * inv};
        *(float4*)&orow[8 * g + 4 * l5]      = r0;
        *(float4*)&orow[32 + 8 * g + 4 * l5] = r1;
    }
}

// ---------------------------------------------------------------- launcher
extern "C" void kernel_launch(void* const* d_in, const int* in_sizes, int n_in,
                              void* d_out, int out_size, void* d_ws, size_t ws_size,
                              hipStream_t stream) {
    const float* hid  = (const float*)d_in[0];
    const float* enc  = (const float*)d_in[1];
    const float* mask = (const float*)d_in[2];
    const float* Wq   = (const float*)d_in[3];
    const float* bq   = (const float*)d_in[4];
    const float* Wk   = (const float*)d_in[5];
    const float* bk   = (const float*)d_in[6];
    const float* Wv   = (const float*)d_in[7];
    const float* bv   = (const float*)d_in[8];
    float* out = (float*)d_out;

    char* ws = (char*)d_ws;
    f16* Wtq  = (f16*)(ws + ((size_t)0 << 20));
    f16* Wtk  = (f16*)(ws + ((size_t)2 << 20));
    f16* Wtv  = (f16*)(ws + ((size_t)4 << 20));
    f16* Aall = (f16*)(ws + ((size_t)6 << 20));   // 16 MiB
    f16* Qw   = (f16*)(ws + ((size_t)22 << 20));  // 8 MiB
    f16* Kw   = (f16*)(ws + ((size_t)30 << 20));  // 16 MiB
    f16* Vtw  = (f16*)(ws + ((size_t)46 << 20));  // 16 MiB
    float* maskS = (float*)(ws + ((size_t)62 << 20)); // 32 KiB

    wt_kernel<<<dim3(32, 32, 3), dim3(32, 8), 0, stream>>>(Wq, Wk, Wv, Wtq, Wtk, Wtv);
    cvt_kernel<<<4096, 256, 0, stream>>>(hid, enc, Aall);
    maskscale_kernel<<<8, 256, 0, stream>>>(mask, maskS);

    qkv_gemm<<<dim3(32, 8), 256, 0, stream>>>(Aall, Wtq, bq, Qw, 0);
    qkv_gemm<<<dim3(64, 8), 256, 0, stream>>>(Aall, Wtk, bk, Kw, 1);
    qkv_gemm<<<dim3(64, 8), 256, 0, stream>>>(Aall, Wtv, bv, Vtw, 2);

    attn_kernel<<<dim3(8, 64), 256, 0, stream>>>(Qw, Kw, Vtw, maskS, out);
}

// Round 10
// 155.087 us; speedup vs baseline: 1.5508x; 1.1246x over previous
//
#include <hip/hip_runtime.h>

// IncrementalRobertaSelfAttentionCross: B=4, Sq=1024, Skv=2048 (enc||dec), D=1024, H=16, HD=64
// Pipeline: Wt transpose (z-fused) + A cast -> fused QKV GEMM (dbuf global_load_lds, 1 barrier/K-step)
//           -> flash attn (dbuf LDS staging, 1 barrier/tile, mask-in-LDS C-init, XCD remap).

typedef _Float16 f16;
typedef __attribute__((ext_vector_type(4))) _Float16 half4;
typedef __attribute__((ext_vector_type(8))) _Float16 half8;
typedef __attribute__((ext_vector_type(4))) float floatx4;
typedef __attribute__((ext_vector_type(16))) float floatx16;
typedef __attribute__((ext_vector_type(4))) unsigned int uint4v;

#define GLOAD16(gp, lp)                                                        \
    __builtin_amdgcn_global_load_lds(                                          \
        (const __attribute__((address_space(1))) void*)(gp),                   \
        (__attribute__((address_space(3))) void*)(lp), 16, 0, 0)

// ---------------------------------------------------------------- W transpose (all 3 via z)
__global__ void wt_kernel(const float* __restrict__ Wq, const float* __restrict__ Wk,
                          const float* __restrict__ Wv, f16* __restrict__ Wtq,
                          f16* __restrict__ Wtk, f16* __restrict__ Wtv) {
    __shared__ float tile[32][33];
    const float* W = (blockIdx.z == 0) ? Wq : (blockIdx.z == 1) ? Wk : Wv;
    f16* Wt = (blockIdx.z == 0) ? Wtq : (blockIdx.z == 1) ? Wtk : Wtv;
    int k0 = blockIdx.y * 32, n0 = blockIdx.x * 32;
    int tx = threadIdx.x, ty = threadIdx.y;   // block (32,8)
    #pragma unroll
    for (int i = 0; i < 32; i += 8)
        tile[ty + i][tx] = W[(k0 + ty + i) * 1024 + n0 + tx];
    __syncthreads();
    #pragma unroll
    for (int i = 0; i < 32; i += 8)
        Wt[(n0 + ty + i) * 1024 + k0 + tx] = (f16)tile[tx][ty + i];
}

// ---------------------------------------------------------------- A cast
__global__ void cvt_kernel(const float* __restrict__ hid, const float* __restrict__ enc,
                           f16* __restrict__ Aall) {
    int t = blockIdx.x * 256 + threadIdx.x;
    int rowg = t >> 7, col = (t & 127) * 8;
    int b = rowg >> 11, r = rowg & 2047;
    const float* src = (r < 1024 ? enc + ((size_t)b * 1024 + r) * 1024
                                 : hid + ((size_t)b * 1024 + (r - 1024)) * 1024) + col;
    float4 v0 = *(const float4*)src, v1 = *(const float4*)(src + 4);
    half8 o;
    o[0] = (f16)v0.x; o[1] = (f16)v0.y; o[2] = (f16)v0.z; o[3] = (f16)v0.w;
    o[4] = (f16)v1.x; o[5] = (f16)v1.y; o[6] = (f16)v1.z; o[7] = (f16)v1.w;
    *(half8*)(Aall + (size_t)rowg * 1024 + col) = o;
}

// ---------------------------------------------------------------- fused QKV GEMM
// z=0: Q -> [bh][s][64] (x<32); z=1: K -> [bh][s][64]; z=2: V -> [bh][d][s] (V^T)
// Double-buffered global_load_lds staging, ONE barrier per K-step.
__launch_bounds__(256)
__global__ void qkv_gemm(const f16* __restrict__ Aall,
                         const f16* __restrict__ Wtq, const f16* __restrict__ Wtk,
                         const f16* __restrict__ Wtv,
                         const float* __restrict__ bq, const float* __restrict__ bk,
                         const float* __restrict__ bv,
                         f16* __restrict__ Qw, f16* __restrict__ Kw, f16* __restrict__ Vtw) {
    int mode = blockIdx.z;
    if (mode == 0 && blockIdx.x >= 32) return;
    __shared__ f16 As[2][128 * 32];
    __shared__ f16 Bs[2][128 * 32];

    const f16* Wt = (mode == 0) ? Wtq : (mode == 1) ? Wtk : Wtv;
    const float* bias = (mode == 0) ? bq : (mode == 1) ? bk : bv;
    f16* out = (mode == 0) ? Qw : (mode == 1) ? Kw : Vtw;

    int tid = threadIdx.x;
    int m0 = blockIdx.x * 128, n0 = blockIdx.y * 128;
    int wid = tid >> 6, lane = tid & 63;
    int wm = (wid >> 1) * 64, wn = (wid & 1) * 64;
    int lr = lane & 15, lg = lane >> 4;

    floatx4 acc[4][4];
    #pragma unroll
    for (int i = 0; i < 4; i++)
        #pragma unroll
        for (int j = 0; j < 4; j++) acc[i][j] = (floatx4)(0.f);

    // staging: thread t covers rows (t>>2), (t>>2)+64, 16B col chunk (t&3)
    int trow = tid >> 2, tcol = (tid & 3) * 8;
    const f16 *a0g, *a1g;
    {
        int mA0 = m0 + trow, mA1 = mA0 + 64;
        if (mode == 0) {
            int b0 = mA0 >> 10, b1 = mA1 >> 10;
            a0g = Aall + ((size_t)(b0 * 2048 + 1024 + (mA0 & 1023))) * 1024 + tcol;
            a1g = Aall + ((size_t)(b1 * 2048 + 1024 + (mA1 & 1023))) * 1024 + tcol;
        } else {
            a0g = Aall + (size_t)mA0 * 1024 + tcol;
            a1g = Aall + (size_t)mA1 * 1024 + tcol;
        }
    }
    const f16* b0g = Wt + (size_t)(n0 + trow) * 1024 + tcol;
    const f16* b1g = Wt + (size_t)(n0 + trow + 64) * 1024 + tcol;

    // prologue: stage tile 0 into buf 0
    GLOAD16(a0g, &As[0][tid * 8]);
    GLOAD16(a1g, &As[0][tid * 8 + 2048]);
    GLOAD16(b0g, &Bs[0][tid * 8]);
    GLOAD16(b1g, &Bs[0][tid * 8 + 2048]);
    __syncthreads();

    int cur = 0;
    for (int k0 = 0; k0 < 1024; k0 += 32) {
        if (k0 < 992) {   // stage next tile into the other buffer (in flight during MFMA)
            int nx = cur ^ 1;
            GLOAD16(a0g + k0 + 32, &As[nx][tid * 8]);
            GLOAD16(a1g + k0 + 32, &As[nx][tid * 8 + 2048]);
            GLOAD16(b0g + k0 + 32, &Bs[nx][tid * 8]);
            GLOAD16(b1g + k0 + 32, &Bs[nx][tid * 8 + 2048]);
        }
        half8 a[4], bf[4];
        #pragma unroll
        for (int i = 0; i < 4; i++)
            a[i] = *(const half8*)&As[cur][(wm + i * 16 + lr) * 32 + lg * 8];
        #pragma unroll
        for (int j = 0; j < 4; j++)
            bf[j] = *(const half8*)&Bs[cur][(wn + j * 16 + lr) * 32 + lg * 8];
        __builtin_amdgcn_s_setprio(1);
        #pragma unroll
        for (int i = 0; i < 4; i++)
            #pragma unroll
            for (int j = 0; j < 4; j++)
                acc[i][j] = __builtin_amdgcn_mfma_f32_16x16x32_f16(a[i], bf[j], acc[i][j], 0, 0, 0);
        __builtin_amdgcn_s_setprio(0);
        __syncthreads();   // drains this iter's gloads (next buf ready) + all ds_reads
        cur ^= 1;
    }

    if (mode == 2) {
        #pragma unroll
        for (int i = 0; i < 4; i++) {
            int mbase = m0 + wm + i * 16 + lg * 4;
            int b = mbase >> 11, s = mbase & 2047;
            #pragma unroll
            for (int j = 0; j < 4; j++) {
                int n = n0 + wn + j * 16 + lr;
                int h = n >> 6, d = n & 63;
                float bv = bias[n];
                half4 w;
                #pragma unroll
                for (int r = 0; r < 4; r++) w[r] = (f16)(acc[i][j][r] + bv);
                *(half4*)(out + ((size_t)((b * 16 + h) * 64 + d)) * 2048 + s) = w;
            }
        }
    } else {
        int Sout = (mode == 0) ? 1024 : 2048;
        #pragma unroll
        for (int i = 0; i < 4; i++) {
            int mbase = m0 + wm + i * 16 + lg * 4;
            #pragma unroll
            for (int j = 0; j < 4; j++) {
                int n = n0 + wn + j * 16 + lr;
                int h = n >> 6, d = n & 63;
                float bv = bias[n];
                #pragma unroll
                for (int r = 0; r < 4; r++) {
                    int m = mbase + r;
                    int b = (mode == 0) ? (m >> 10) : (m >> 11);
                    int s = (mode == 0) ? (m & 1023) : (m & 2047);
                    out[((size_t)(b * 16 + h) * Sout + s) * 64 + d] = (f16)(acc[i][j][r] + bv);
                }
            }
        }
    }
}

// ---------------------------------------------------------------- flash attention
__device__ inline half8 pack_swap(float s0, float s1, float s2, float s3,
                                  float s4, float s5, float s6, float s7) {
    unsigned a0 = __builtin_bit_cast(unsigned, __builtin_amdgcn_cvt_pkrtz(s0, s1));
    unsigned b0 = __builtin_bit_cast(unsigned, __builtin_amdgcn_cvt_pkrtz(s4, s5));
    unsigned a1 = __builtin_bit_cast(unsigned, __builtin_amdgcn_cvt_pkrtz(s2, s3));
    unsigned b1 = __builtin_bit_cast(unsigned, __builtin_amdgcn_cvt_pkrtz(s6, s7));
    asm("v_permlane32_swap_b32 %0, %1" : "+v"(a0), "+v"(b0));
    asm("v_permlane32_swap_b32 %0, %1" : "+v"(a1), "+v"(b1));
    uint4v w = {a0, a1, b0, b1};
    return __builtin_bit_cast(half8, w);
}

__device__ inline half8 pack_noswap(float s0, float s1, float s2, float s3,
                                    float s4, float s5, float s6, float s7) {
    unsigned w0 = __builtin_bit_cast(unsigned, __builtin_amdgcn_cvt_pkrtz(s0, s1));
    unsigned w1 = __builtin_bit_cast(unsigned, __builtin_amdgcn_cvt_pkrtz(s2, s3));
    unsigned w2 = __builtin_bit_cast(unsigned, __builtin_amdgcn_cvt_pkrtz(s4, s5));
    unsigned w3 = __builtin_bit_cast(unsigned, __builtin_amdgcn_cvt_pkrtz(s6, s7));
    uint4v w = {w0, w1, w2, w3};
    return __builtin_bit_cast(half8, w);
}

// Q [bh][1024][64], K [bh][2048][64], Vt [bh][64][2048] f16, mask [B][2048] f32.
// Double-buffered LDS staging (1 barrier/tile), mask*log2e staged in LDS once,
// C-init from LDS (broadcast), XCD-bijective block remap, defer-max with floor init.
__launch_bounds__(256)
__global__ void attn_kernel(const f16* __restrict__ Q, const f16* __restrict__ K,
                            const f16* __restrict__ Vt, const float* __restrict__ mask,
                            float* __restrict__ out) {
    __shared__ f16 Kt[2][64 * 72];
    __shared__ f16 Vtt[2][64 * 72];
    __shared__ float maskLds[2048];

    const float LOG2E = 1.4426950408889634f;
    int tid = threadIdx.x;
    int wid = tid >> 6, lane = tid & 63;
    int l31 = lane & 31, l5 = lane >> 5;

    // XCD-bijective remap (r8-validated: FETCH 139->22MB): 8 q-blocks of one bh per XCD
    int bid = blockIdx.x + 8 * blockIdx.y;   // grid (8,64) = 512
    int xcd = bid & 7, w = bid >> 3;
    int bh = xcd * 8 + (w >> 3);
    int xblk = w & 7;
    int b = bh >> 4;
    int q = xblk * 128 + wid * 32 + l31;

    // runtime probe of the 32x32x16 B-operand k-layout (flat vs two-block)
    half8 pa, pcode;
    #pragma unroll
    for (int j = 0; j < 8; j++) { pa[j] = (f16)0; pcode[j] = (f16)(8 * l5 + j); }
    if (l31 < 16 && (l31 >> 3) == l5) pa[l31 & 7] = (f16)1;
    floatx16 pd = __builtin_amdgcn_mfma_f32_32x32x16_f16(pa, pcode, (floatx16)0.f, 0, 0, 0);
    float r4 = __shfl(pd[0], 32);
    bool twoblk = (r4 > 6.0f);

    // stage mask * log2e into LDS
    const float* maskp = mask + b * 2048;
    for (int i = tid; i < 512; i += 256) {
        float4 mv = ((const float4*)maskp)[i];
        mv.x *= LOG2E; mv.y *= LOG2E; mv.z *= LOG2E; mv.w *= LOG2E;
        ((float4*)maskLds)[i] = mv;
    }

    // Q frags pre-scaled by 0.125*log2e, per probed B k-map
    const f16* qrow = Q + ((size_t)bh * 1024 + q) * 64;
    half8 qf[4];
    if (!twoblk) {
        #pragma unroll
        for (int ks = 0; ks < 4; ks++)
            qf[ks] = *(const half8*)(qrow + ks * 16 + l5 * 8);
    } else {
        #pragma unroll
        for (int ks = 0; ks < 4; ks++) {
            half4 lo = *(const half4*)(qrow + ks * 16 + 4 * l5);
            half4 hi = *(const half4*)(qrow + ks * 16 + 8 + 4 * l5);
            qf[ks][0] = lo[0]; qf[ks][1] = lo[1]; qf[ks][2] = lo[2]; qf[ks][3] = lo[3];
            qf[ks][4] = hi[0]; qf[ks][5] = hi[1]; qf[ks][6] = hi[2]; qf[ks][7] = hi[3];
        }
    }
    const f16 qs = (f16)(0.125f * 1.4426950408889634f);
    #pragma unroll
    for (int ks = 0; ks < 4; ks++)
        #pragma unroll
        for (int x = 0; x < 8; x++) qf[ks][x] *= qs;

    floatx16 o0 = (floatx16)0.f, o1 = (floatx16)0.f;
    float m_run = 8.0f, l_run = 0.f;   // floor init: first-tile rescale never fires

    int sr = tid >> 2, sc = (tid & 3) * 16;
    const f16* Ksrc = K + ((size_t)bh * 2048 + sr) * 64 + sc;
    const f16* Vsrc = Vt + ((size_t)(bh * 64 + sr)) * 2048 + sc;

    // prologue: tile 0 -> regs -> buf0; issue tile 1 loads
    half8 rk0 = *(const half8*)(Ksrc);
    half8 rk1 = *(const half8*)(Ksrc + 8);
    half8 rv0 = *(const half8*)(Vsrc);
    half8 rv1 = *(const half8*)(Vsrc + 8);
    *(half8*)&Kt[0][sr * 72 + sc]      = rk0;
    *(half8*)&Kt[0][sr * 72 + sc + 8]  = rk1;
    *(half8*)&Vtt[0][sr * 72 + sc]     = rv0;
    *(half8*)&Vtt[0][sr * 72 + sc + 8] = rv1;
    rk0 = *(const half8*)(Ksrc + (size_t)64 * 64);
    rk1 = *(const half8*)(Ksrc + (size_t)64 * 64 + 8);
    rv0 = *(const half8*)(Vsrc + 64);
    rv1 = *(const half8*)(Vsrc + 64 + 8);
    __syncthreads();

    int cur = 0;
    for (int kv0 = 0; kv0 < 2048; kv0 += 64) {
        // write NEXT tile (regs) into the other buffer; then issue loads for tile+2
        if (kv0 < 2048 - 64) {
            int nx = cur ^ 1;
            *(half8*)&Kt[nx][sr * 72 + sc]      = rk0;
            *(half8*)&Kt[nx][sr * 72 + sc + 8]  = rk1;
            *(half8*)&Vtt[nx][sr * 72 + sc]     = rv0;
            *(half8*)&Vtt[nx][sr * 72 + sc + 8] = rv1;
            if (kv0 < 2048 - 128) {
                rk0 = *(const half8*)(Ksrc + (size_t)(kv0 + 128) * 64);
                rk1 = *(const half8*)(Ksrc + (size_t)(kv0 + 128) * 64 + 8);
                rv0 = *(const half8*)(Vsrc + kv0 + 128);
                rv1 = *(const half8*)(Vsrc + kv0 + 128 + 8);
            }
        }

        // S init = mask (log2 domain) from LDS (broadcast reads)
        floatx16 sf0, sf1;
        #pragma unroll
        for (int g = 0; g < 4; g++) {
            float4 mk0 = *(const float4*)&maskLds[kv0 + 8 * g + 4 * l5];
            float4 mk1 = *(const float4*)&maskLds[kv0 + 32 + 8 * g + 4 * l5];
            #pragma unroll
            for (int i = 0; i < 4; i++) {
                sf0[4 * g + i] = ((const float*)&mk0)[i];
                sf1[4 * g + i] = ((const float*)&mk1)[i];
            }
        }

        // QK^T (swapped): A = K rows (flat), B = Q (probed)
        __builtin_amdgcn_s_setprio(1);
        #pragma unroll
        for (int ks = 0; ks < 4; ks++) {
            half8 k0 = *(const half8*)&Kt[cur][l31 * 72 + ks * 16 + l5 * 8];
            half8 k1 = *(const half8*)&Kt[cur][(32 + l31) * 72 + ks * 16 + l5 * 8];
            sf0 = __builtin_amdgcn_mfma_f32_32x32x16_f16(k0, qf[ks], sf0, 0, 0, 0);
            sf1 = __builtin_amdgcn_mfma_f32_32x32x16_f16(k1, qf[ks], sf1, 0, 0, 0);
        }
        __builtin_amdgcn_s_setprio(0);

        float pmax = -1e30f;
        #pragma unroll
        for (int r = 0; r < 16; r++)
            pmax = fmaxf(pmax, fmaxf(sf0[r], sf1[r]));

        // defer-max rescale (THR=8, log2 units)
        if (!__all(pmax - m_run <= 8.0f)) {
            float rmax = fmaxf(pmax, __shfl_xor(pmax, 32));
            float mnew = fmaxf(m_run, rmax);
            float alpha = exp2f(m_run - mnew);
            l_run *= alpha;
            #pragma unroll
            for (int r = 0; r < 16; r++) { o0[r] *= alpha; o1[r] *= alpha; }
            m_run = mnew;
        }

        float ls = 0.f;
        #pragma unroll
        for (int r = 0; r < 16; r++) {
            float p0 = exp2f(sf0[r] - m_run);
            float p1 = exp2f(sf1[r] - m_run);
            sf0[r] = p0; sf1[r] = p1;
            ls += p0 + p1;
        }
        ls += __shfl_xor(ls, 32);
        l_run += ls;

        half8 pb[4];
        if (!twoblk) {
            pb[0] = pack_swap(sf0[0], sf0[1], sf0[2], sf0[3], sf0[4], sf0[5], sf0[6], sf0[7]);
            pb[1] = pack_swap(sf0[8], sf0[9], sf0[10], sf0[11], sf0[12], sf0[13], sf0[14], sf0[15]);
            pb[2] = pack_swap(sf1[0], sf1[1], sf1[2], sf1[3], sf1[4], sf1[5], sf1[6], sf1[7]);
            pb[3] = pack_swap(sf1[8], sf1[9], sf1[10], sf1[11], sf1[12], sf1[13], sf1[14], sf1[15]);
        } else {
            pb[0] = pack_noswap(sf0[0], sf0[1], sf0[2], sf0[3], sf0[4], sf0[5], sf0[6], sf0[7]);
            pb[1] = pack_noswap(sf0[8], sf0[9], sf0[10], sf0[11], sf0[12], sf0[13], sf0[14], sf0[15]);
            pb[2] = pack_noswap(sf1[0], sf1[1], sf1[2], sf1[3], sf1[4], sf1[5], sf1[6], sf1[7]);
            pb[3] = pack_noswap(sf1[8], sf1[9], sf1[10], sf1[11], sf1[12], sf1[13], sf1[14], sf1[15]);
        }

        // PV (swapped): O^T[d][q] += V^T[d][kv] P^T[kv][q]
        __builtin_amdgcn_s_setprio(1);
        #pragma unroll
        for (int kb = 0; kb < 4; kb++) {
            half8 v0 = *(const half8*)&Vtt[cur][l31 * 72 + kb * 16 + l5 * 8];
            half8 v1 = *(const half8*)&Vtt[cur][(32 + l31) * 72 + kb * 16 + l5 * 8];
            o0 = __builtin_amdgcn_mfma_f32_32x32x16_f16(v0, pb[kb], o0, 0, 0, 0);
            o1 = __builtin_amdgcn_mfma_f32_32x32x16_f16(v1, pb[kb], o1, 0, 0, 0);
        }
        __builtin_amdgcn_s_setprio(0);

        __syncthreads();   // next buffer's ds_writes visible; this buffer's reads done
        cur ^= 1;
    }

    // epilogue: o[dt][r] is O^T[d = dt*32 + (r&3)+8*(r>>2)+4*l5][q = l31]
    int h = bh & 15;
    float inv = 1.f / l_run;
    float* orow = out + ((size_t)(b * 1024 + q)) * 1024 + h * 64;
    #pragma unroll
    for (int g = 0; g < 4; g++) {
        float4 r0 = {o0[4 * g] * inv, o0[4 * g + 1] * inv, o0[4 * g + 2] * inv, o0[4 * g + 3] * inv};
        float4 r1 = {o1[4 * g] * inv, o1[4 * g + 1] * inv, o1[4 * g + 2] * inv, o1[4 * g + 3] * inv};
        *(float4*)&orow[8 * g + 4 * l5]      = r0;
        *(float4*)&orow[32 + 8 * g + 4 * l5] = r1;
    }
}

// ---------------------------------------------------------------- launcher
extern "C" void kernel_launch(void* const* d_in, const int* in_sizes, int n_in,
                              void* d_out, int out_size, void* d_ws, size_t ws_size,
                              hipStream_t stream) {
    const float* hid  = (const float*)d_in[0];
    const float* enc  = (const float*)d_in[1];
    const float* mask = (const float*)d_in[2];
    const float* Wq   = (const float*)d_in[3];
    const float* bq   = (const float*)d_in[4];
    const float* Wk   = (const float*)d_in[5];
    const float* bk   = (const float*)d_in[6];
    const float* Wv   = (const float*)d_in[7];
    const float* bv   = (const float*)d_in[8];
    float* out = (float*)d_out;

    char* ws = (char*)d_ws;
    f16* Wtq  = (f16*)(ws + ((size_t)0 << 20));
    f16* Wtk  = (f16*)(ws + ((size_t)2 << 20));
    f16* Wtv  = (f16*)(ws + ((size_t)4 << 20));
    f16* Aall = (f16*)(ws + ((size_t)6 << 20));   // 16 MiB
    f16* Qw   = (f16*)(ws + ((size_t)22 << 20));  // 8 MiB
    f16* Kw   = (f16*)(ws + ((size_t)30 << 20));  // 16 MiB
    f16* Vtw  = (f16*)(ws + ((size_t)46 << 20));  // 16 MiB

    wt_kernel<<<dim3(32, 32, 3), dim3(32, 8), 0, stream>>>(Wq, Wk, Wv, Wtq, Wtk, Wtv);
    cvt_kernel<<<4096, 256, 0, stream>>>(hid, enc, Aall);

    qkv_gemm<<<dim3(64, 8, 3), 256, 0, stream>>>(Aall, Wtq, Wtk, Wtv, bq, bk, bv, Qw, Kw, Vtw);

    attn_kernel<<<dim3(8, 64), 256, 0, stream>>>(Qw, Kw, Vtw, mask, out);
}

// Round 11
// 150.736 us; speedup vs baseline: 1.5956x; 1.0289x over previous
//
#include <hip/hip_runtime.h>

// IncrementalRobertaSelfAttentionCross: B=4, Sq=1024, Skv=2048 (enc||dec), D=1024, H=16, HD=64
// Pipeline: prep (Wt transpose + A cast, fused) -> fused QKV GEMM (dbuf global_load_lds)
//           -> flash attn (dbuf LDS, MFMA l-sum via ones-row, max3 pmax, XCD remap).

typedef _Float16 f16;
typedef __attribute__((ext_vector_type(4))) _Float16 half4;
typedef __attribute__((ext_vector_type(8))) _Float16 half8;
typedef __attribute__((ext_vector_type(4))) float floatx4;
typedef __attribute__((ext_vector_type(16))) float floatx16;
typedef __attribute__((ext_vector_type(4))) unsigned int uint4v;

#define GLOAD16(gp, lp)                                                        \
    __builtin_amdgcn_global_load_lds(                                          \
        (const __attribute__((address_space(1))) void*)(gp),                   \
        (__attribute__((address_space(3))) void*)(lp), 16, 0, 0)

// ---------------------------------------------------------------- prep: W transposes + A cast
// bid < 3072: transpose W[bid/1024] 32x32 tile; bid >= 3072: A-cast chunk.
__global__ void prep_kernel(const float* __restrict__ hid, const float* __restrict__ enc,
                            const float* __restrict__ Wq, const float* __restrict__ Wk,
                            const float* __restrict__ Wv, f16* __restrict__ Wtq,
                            f16* __restrict__ Wtk, f16* __restrict__ Wtv,
                            f16* __restrict__ Aall) {
    int bid = blockIdx.x, tid = threadIdx.x;
    if (bid < 3072) {
        __shared__ float tile[32][33];
        int z = bid >> 10, xy = bid & 1023;
        const float* W = (z == 0) ? Wq : (z == 1) ? Wk : Wv;
        f16* Wt = (z == 0) ? Wtq : (z == 1) ? Wtk : Wtv;
        int n0 = (xy & 31) * 32, k0 = (xy >> 5) * 32;
        int tx = tid & 31, ty = tid >> 5;   // (32,8)
        #pragma unroll
        for (int i = 0; i < 32; i += 8)
            tile[ty + i][tx] = W[(k0 + ty + i) * 1024 + n0 + tx];
        __syncthreads();
        #pragma unroll
        for (int i = 0; i < 32; i += 8)
            Wt[(n0 + ty + i) * 1024 + k0 + tx] = (f16)tile[tx][ty + i];
    } else {
        int t = (bid - 3072) * 256 + tid;
        int rowg = t >> 7, col = (t & 127) * 8;
        int b = rowg >> 11, r = rowg & 2047;
        const float* src = (r < 1024 ? enc + ((size_t)b * 1024 + r) * 1024
                                     : hid + ((size_t)b * 1024 + (r - 1024)) * 1024) + col;
        float4 v0 = *(const float4*)src, v1 = *(const float4*)(src + 4);
        half8 o;
        o[0] = (f16)v0.x; o[1] = (f16)v0.y; o[2] = (f16)v0.z; o[3] = (f16)v0.w;
        o[4] = (f16)v1.x; o[5] = (f16)v1.y; o[6] = (f16)v1.z; o[7] = (f16)v1.w;
        *(half8*)(Aall + (size_t)rowg * 1024 + col) = o;
    }
}

// ---------------------------------------------------------------- fused QKV GEMM
// z=0: Q -> [bh][s][64] (x<32); z=1: K -> [bh][s][64]; z=2: V -> [bh][d][s] (V^T)
__launch_bounds__(256)
__global__ void qkv_gemm(const f16* __restrict__ Aall,
                         const f16* __restrict__ Wtq, const f16* __restrict__ Wtk,
                         const f16* __restrict__ Wtv,
                         const float* __restrict__ bq, const float* __restrict__ bk,
                         const float* __restrict__ bv,
                         f16* __restrict__ Qw, f16* __restrict__ Kw, f16* __restrict__ Vtw) {
    int mode = blockIdx.z;
    if (mode == 0 && blockIdx.x >= 32) return;
    __shared__ f16 As[2][128 * 32];
    __shared__ f16 Bs[2][128 * 32];

    const f16* Wt = (mode == 0) ? Wtq : (mode == 1) ? Wtk : Wtv;
    const float* bias = (mode == 0) ? bq : (mode == 1) ? bk : bv;
    f16* out = (mode == 0) ? Qw : (mode == 1) ? Kw : Vtw;

    int tid = threadIdx.x;
    int m0 = blockIdx.x * 128, n0 = blockIdx.y * 128;
    int wid = tid >> 6, lane = tid & 63;
    int wm = (wid >> 1) * 64, wn = (wid & 1) * 64;
    int lr = lane & 15, lg = lane >> 4;

    floatx4 acc[4][4];
    #pragma unroll
    for (int i = 0; i < 4; i++)
        #pragma unroll
        for (int j = 0; j < 4; j++) acc[i][j] = (floatx4)(0.f);

    int trow = tid >> 2, tcol = (tid & 3) * 8;
    const f16 *a0g, *a1g;
    {
        int mA0 = m0 + trow, mA1 = mA0 + 64;
        if (mode == 0) {
            int b0 = mA0 >> 10, b1 = mA1 >> 10;
            a0g = Aall + ((size_t)(b0 * 2048 + 1024 + (mA0 & 1023))) * 1024 + tcol;
            a1g = Aall + ((size_t)(b1 * 2048 + 1024 + (mA1 & 1023))) * 1024 + tcol;
        } else {
            a0g = Aall + (size_t)mA0 * 1024 + tcol;
            a1g = Aall + (size_t)mA1 * 1024 + tcol;
        }
    }
    const f16* b0g = Wt + (size_t)(n0 + trow) * 1024 + tcol;
    const f16* b1g = Wt + (size_t)(n0 + trow + 64) * 1024 + tcol;

    GLOAD16(a0g, &As[0][tid * 8]);
    GLOAD16(a1g, &As[0][tid * 8 + 2048]);
    GLOAD16(b0g, &Bs[0][tid * 8]);
    GLOAD16(b1g, &Bs[0][tid * 8 + 2048]);
    __syncthreads();

    int cur = 0;
    for (int k0 = 0; k0 < 1024; k0 += 32) {
        if (k0 < 992) {
            int nx = cur ^ 1;
            GLOAD16(a0g + k0 + 32, &As[nx][tid * 8]);
            GLOAD16(a1g + k0 + 32, &As[nx][tid * 8 + 2048]);
            GLOAD16(b0g + k0 + 32, &Bs[nx][tid * 8]);
            GLOAD16(b1g + k0 + 32, &Bs[nx][tid * 8 + 2048]);
        }
        half8 a[4], bf[4];
        #pragma unroll
        for (int i = 0; i < 4; i++)
            a[i] = *(const half8*)&As[cur][(wm + i * 16 + lr) * 32 + lg * 8];
        #pragma unroll
        for (int j = 0; j < 4; j++)
            bf[j] = *(const half8*)&Bs[cur][(wn + j * 16 + lr) * 32 + lg * 8];
        __builtin_amdgcn_s_setprio(1);
        #pragma unroll
        for (int i = 0; i < 4; i++)
            #pragma unroll
            for (int j = 0; j < 4; j++)
                acc[i][j] = __builtin_amdgcn_mfma_f32_16x16x32_f16(a[i], bf[j], acc[i][j], 0, 0, 0);
        __builtin_amdgcn_s_setprio(0);
        __syncthreads();
        cur ^= 1;
    }

    if (mode == 2) {
        #pragma unroll
        for (int i = 0; i < 4; i++) {
            int mbase = m0 + wm + i * 16 + lg * 4;
            int b = mbase >> 11, s = mbase & 2047;
            #pragma unroll
            for (int j = 0; j < 4; j++) {
                int n = n0 + wn + j * 16 + lr;
                int h = n >> 6, d = n & 63;
                float bv = bias[n];
                half4 w;
                #pragma unroll
                for (int r = 0; r < 4; r++) w[r] = (f16)(acc[i][j][r] + bv);
                *(half4*)(out + ((size_t)((b * 16 + h) * 64 + d)) * 2048 + s) = w;
            }
        }
    } else {
        int Sout = (mode == 0) ? 1024 : 2048;
        #pragma unroll
        for (int i = 0; i < 4; i++) {
            int mbase = m0 + wm + i * 16 + lg * 4;
            #pragma unroll
            for (int j = 0; j < 4; j++) {
                int n = n0 + wn + j * 16 + lr;
                int h = n >> 6, d = n & 63;
                float bv = bias[n];
                #pragma unroll
                for (int r = 0; r < 4; r++) {
                    int m = mbase + r;
                    int b = (mode == 0) ? (m >> 10) : (m >> 11);
                    int s = (mode == 0) ? (m & 1023) : (m & 2047);
                    out[((size_t)(b * 16 + h) * Sout + s) * 64 + d] = (f16)(acc[i][j][r] + bv);
                }
            }
        }
    }
}

// ---------------------------------------------------------------- flash attention
__device__ inline half8 pack_swap(float s0, float s1, float s2, float s3,
                                  float s4, float s5, float s6, float s7) {
    unsigned a0 = __builtin_bit_cast(unsigned, __builtin_amdgcn_cvt_pkrtz(s0, s1));
    unsigned b0 = __builtin_bit_cast(unsigned, __builtin_amdgcn_cvt_pkrtz(s4, s5));
    unsigned a1 = __builtin_bit_cast(unsigned, __builtin_amdgcn_cvt_pkrtz(s2, s3));
    unsigned b1 = __builtin_bit_cast(unsigned, __builtin_amdgcn_cvt_pkrtz(s6, s7));
    asm("v_permlane32_swap_b32 %0, %1" : "+v"(a0), "+v"(b0));
    asm("v_permlane32_swap_b32 %0, %1" : "+v"(a1), "+v"(b1));
    uint4v w = {a0, a1, b0, b1};
    return __builtin_bit_cast(half8, w);
}

__device__ inline half8 pack_noswap(float s0, float s1, float s2, float s3,
                                    float s4, float s5, float s6, float s7) {
    unsigned w0 = __builtin_bit_cast(unsigned, __builtin_amdgcn_cvt_pkrtz(s0, s1));
    unsigned w1 = __builtin_bit_cast(unsigned, __builtin_amdgcn_cvt_pkrtz(s2, s3));
    unsigned w2 = __builtin_bit_cast(unsigned, __builtin_amdgcn_cvt_pkrtz(s4, s5));
    unsigned w3 = __builtin_bit_cast(unsigned, __builtin_amdgcn_cvt_pkrtz(s6, s7));
    uint4v w = {w0, w1, w2, w3};
    return __builtin_bit_cast(half8, w);
}

#define SS(r) ((r) < 16 ? sf0[(r)] : sf1[(r) - 16])

// Q [bh][1024][64], K [bh][2048][64], Vt [bh][64][2048] f16, mask [B][2048] f32.
// dbuf LDS (1 barrier/tile), mask*log2e in LDS C-init, MFMA l-sum (o2, ones row),
// max3 pmax, XCD-bijective remap, defer-max with floor init.
__launch_bounds__(256)
__global__ void attn_kernel(const f16* __restrict__ Q, const f16* __restrict__ K,
                            const f16* __restrict__ Vt, const float* __restrict__ mask,
                            float* __restrict__ out) {
    __shared__ f16 Kt[2][64 * 72];
    __shared__ f16 Vtt[2][64 * 72];
    __shared__ float maskLds[2048];

    const float LOG2E = 1.4426950408889634f;
    int tid = threadIdx.x;
    int wid = tid >> 6, lane = tid & 63;
    int l31 = lane & 31, l5 = lane >> 5;

    // XCD-bijective remap (r8-validated): 8 q-blocks of one bh per XCD
    int bid = blockIdx.x + 8 * blockIdx.y;   // grid (8,64) = 512
    int xcd = bid & 7, w = bid >> 3;
    int bh = xcd * 8 + (w >> 3);
    int xblk = w & 7;
    int b = bh >> 4;
    int q = xblk * 128 + wid * 32 + l31;

    // runtime probe of the 32x32x16 B-operand k-layout (flat vs two-block)
    half8 pa, pcode;
    #pragma unroll
    for (int j = 0; j < 8; j++) { pa[j] = (f16)0; pcode[j] = (f16)(8 * l5 + j); }
    if (l31 < 16 && (l31 >> 3) == l5) pa[l31 & 7] = (f16)1;
    floatx16 pd = __builtin_amdgcn_mfma_f32_32x32x16_f16(pa, pcode, (floatx16)0.f, 0, 0, 0);
    float r4 = __shfl(pd[0], 32);
    bool twoblk = (r4 > 6.0f);

    // stage mask * log2e into LDS
    const float* maskp = mask + b * 2048;
    for (int i = tid; i < 512; i += 256) {
        float4 mv = ((const float4*)maskp)[i];
        mv.x *= LOG2E; mv.y *= LOG2E; mv.z *= LOG2E; mv.w *= LOG2E;
        ((float4*)maskLds)[i] = mv;
    }

    // Q frags pre-scaled by 0.125*log2e, per probed B k-map
    const f16* qrow = Q + ((size_t)bh * 1024 + q) * 64;
    half8 qf[4];
    if (!twoblk) {
        #pragma unroll
        for (int ks = 0; ks < 4; ks++)
            qf[ks] = *(const half8*)(qrow + ks * 16 + l5 * 8);
    } else {
        #pragma unroll
        for (int ks = 0; ks < 4; ks++) {
            half4 lo = *(const half4*)(qrow + ks * 16 + 4 * l5);
            half4 hi = *(const half4*)(qrow + ks * 16 + 8 + 4 * l5);
            qf[ks][0] = lo[0]; qf[ks][1] = lo[1]; qf[ks][2] = lo[2]; qf[ks][3] = lo[3];
            qf[ks][4] = hi[0]; qf[ks][5] = hi[1]; qf[ks][6] = hi[2]; qf[ks][7] = hi[3];
        }
    }
    const f16 qs = (f16)(0.125f * 1.4426950408889634f);
    #pragma unroll
    for (int ks = 0; ks < 4; ks++)
        #pragma unroll
        for (int x = 0; x < 8; x++) qf[ks][x] *= qs;

    // ones A-row for MFMA l-sum (row 0 of A = 1, layout-independent)
    half8 aones;
    #pragma unroll
    for (int j = 0; j < 8; j++) aones[j] = (l31 == 0) ? (f16)1 : (f16)0;

    floatx16 o0 = (floatx16)0.f, o1 = (floatx16)0.f, o2 = (floatx16)0.f;
    float m_run = 8.0f;   // floor init: first-tile rescale never fires

    int sr = tid >> 2, sc = (tid & 3) * 16;
    const f16* Ksrc = K + ((size_t)bh * 2048 + sr) * 64 + sc;
    const f16* Vsrc = Vt + ((size_t)(bh * 64 + sr)) * 2048 + sc;

    // prologue: tile 0 -> regs -> buf0; prefetch tile 1
    half8 rk0 = *(const half8*)(Ksrc);
    half8 rk1 = *(const half8*)(Ksrc + 8);
    half8 rv0 = *(const half8*)(Vsrc);
    half8 rv1 = *(const half8*)(Vsrc + 8);
    *(half8*)&Kt[0][sr * 72 + sc]      = rk0;
    *(half8*)&Kt[0][sr * 72 + sc + 8]  = rk1;
    *(half8*)&Vtt[0][sr * 72 + sc]     = rv0;
    *(half8*)&Vtt[0][sr * 72 + sc + 8] = rv1;
    rk0 = *(const half8*)(Ksrc + (size_t)64 * 64);
    rk1 = *(const half8*)(Ksrc + (size_t)64 * 64 + 8);
    rv0 = *(const half8*)(Vsrc + 64);
    rv1 = *(const half8*)(Vsrc + 64 + 8);
    __syncthreads();

    int cur = 0;
    for (int kv0 = 0; kv0 < 2048; kv0 += 64) {
        if (kv0 < 2048 - 64) {
            int nx = cur ^ 1;
            *(half8*)&Kt[nx][sr * 72 + sc]      = rk0;
            *(half8*)&Kt[nx][sr * 72 + sc + 8]  = rk1;
            *(half8*)&Vtt[nx][sr * 72 + sc]     = rv0;
            *(half8*)&Vtt[nx][sr * 72 + sc + 8] = rv1;
            if (kv0 < 2048 - 128) {
                rk0 = *(const half8*)(Ksrc + (size_t)(kv0 + 128) * 64);
                rk1 = *(const half8*)(Ksrc + (size_t)(kv0 + 128) * 64 + 8);
                rv0 = *(const half8*)(Vsrc + kv0 + 128);
                rv1 = *(const half8*)(Vsrc + kv0 + 128 + 8);
            }
        }

        // S init = mask (log2 domain) from LDS
        floatx16 sf0, sf1;
        #pragma unroll
        for (int g = 0; g < 4; g++) {
            float4 mk0 = *(const float4*)&maskLds[kv0 + 8 * g + 4 * l5];
            float4 mk1 = *(const float4*)&maskLds[kv0 + 32 + 8 * g + 4 * l5];
            #pragma unroll
            for (int i = 0; i < 4; i++) {
                sf0[4 * g + i] = ((const float*)&mk0)[i];
                sf1[4 * g + i] = ((const float*)&mk1)[i];
            }
        }

        // QK^T (swapped): A = K rows (flat), B = Q (probed)
        __builtin_amdgcn_s_setprio(1);
        #pragma unroll
        for (int ks = 0; ks < 4; ks++) {
            half8 k0 = *(const half8*)&Kt[cur][l31 * 72 + ks * 16 + l5 * 8];
            half8 k1 = *(const half8*)&Kt[cur][(32 + l31) * 72 + ks * 16 + l5 * 8];
            sf0 = __builtin_amdgcn_mfma_f32_32x32x16_f16(k0, qf[ks], sf0, 0, 0, 0);
            sf1 = __builtin_amdgcn_mfma_f32_32x32x16_f16(k1, qf[ks], sf1, 0, 0, 0);
        }
        __builtin_amdgcn_s_setprio(0);

        // pmax via max3 tree (~16 ops)
        float mx[11];
        #pragma unroll
        for (int t = 0; t < 10; t++)
            mx[t] = fmaxf(fmaxf(SS(3 * t), SS(3 * t + 1)), SS(3 * t + 2));
        mx[10] = fmaxf(SS(30), SS(31));
        float pmax = fmaxf(fmaxf(mx[0], mx[1]), mx[2]);
        float p2 = fmaxf(fmaxf(mx[3], mx[4]), mx[5]);
        float p3 = fmaxf(fmaxf(mx[6], mx[7]), mx[8]);
        float p4 = fmaxf(fmaxf(mx[9], mx[10]), pmax);
        pmax = fmaxf(fmaxf(p2, p3), p4);

        // defer-max rescale (THR=8, log2 units)
        if (!__all(pmax - m_run <= 8.0f)) {
            float rmax = fmaxf(pmax, __shfl_xor(pmax, 32));
            float mnew = fmaxf(m_run, rmax);
            float alpha = exp2f(m_run - mnew);
            #pragma unroll
            for (int r = 0; r < 16; r++) { o0[r] *= alpha; o1[r] *= alpha; o2[r] *= alpha; }
            m_run = mnew;
        }

        // exp2 (sum now via MFMA ones-row)
        #pragma unroll
        for (int r = 0; r < 16; r++) {
            sf0[r] = exp2f(sf0[r] - m_run);
            sf1[r] = exp2f(sf1[r] - m_run);
        }

        half8 pb[4];
        if (!twoblk) {
            pb[0] = pack_swap(sf0[0], sf0[1], sf0[2], sf0[3], sf0[4], sf0[5], sf0[6], sf0[7]);
            pb[1] = pack_swap(sf0[8], sf0[9], sf0[10], sf0[11], sf0[12], sf0[13], sf0[14], sf0[15]);
            pb[2] = pack_swap(sf1[0], sf1[1], sf1[2], sf1[3], sf1[4], sf1[5], sf1[6], sf1[7]);
            pb[3] = pack_swap(sf1[8], sf1[9], sf1[10], sf1[11], sf1[12], sf1[13], sf1[14], sf1[15]);
        } else {
            pb[0] = pack_noswap(sf0[0], sf0[1], sf0[2], sf0[3], sf0[4], sf0[5], sf0[6], sf0[7]);
            pb[1] = pack_noswap(sf0[8], sf0[9], sf0[10], sf0[11], sf0[12], sf0[13], sf0[14], sf0[15]);
            pb[2] = pack_noswap(sf1[0], sf1[1], sf1[2], sf1[3], sf1[4], sf1[5], sf1[6], sf1[7]);
            pb[3] = pack_noswap(sf1[8], sf1[9], sf1[10], sf1[11], sf1[12], sf1[13], sf1[14], sf1[15]);
        }

        // PV (swapped) + MFMA l-sum: O^T += V^T P^T;  o2 row0 += 1^T P^T
        __builtin_amdgcn_s_setprio(1);
        #pragma unroll
        for (int kb = 0; kb < 4; kb++) {
            half8 v0 = *(const half8*)&Vtt[cur][l31 * 72 + kb * 16 + l5 * 8];
            half8 v1 = *(const half8*)&Vtt[cur][(32 + l31) * 72 + kb * 16 + l5 * 8];
            o0 = __builtin_amdgcn_mfma_f32_32x32x16_f16(v0, pb[kb], o0, 0, 0, 0);
            o1 = __builtin_amdgcn_mfma_f32_32x32x16_f16(v1, pb[kb], o1, 0, 0, 0);
            o2 = __builtin_amdgcn_mfma_f32_32x32x16_f16(aones, pb[kb], o2, 0, 0, 0);
        }
        __builtin_amdgcn_s_setprio(0);

        __syncthreads();
        cur ^= 1;
    }

    // l lives in o2 reg0 of l5=0 lanes (row 0, col q=l31); broadcast to l5=1 half
    float l_all = __shfl(o2[0], l31);
    int h = bh & 15;
    float inv = 1.f / l_all;
    float* orow = out + ((size_t)(b * 1024 + q)) * 1024 + h * 64;
    #pragma unroll
    for (int g = 0; g < 4; g++) {
        float4 r0 = {o0[4 * g] * inv, o0[4 * g + 1] * inv, o0[4 * g + 2] * inv, o0[4 * g + 3] * inv};
        float4 r1 = {o1[4 * g] * inv, o1[4 * g + 1] * inv, o1[4 * g + 2] * inv, o1[4 * g + 3] * inv};
        *(float4*)&orow[8 * g + 4 * l5]      = r0;
        *(float4*)&orow[32 + 8 * g + 4 * l5] = r1;
    }
}

// ---------------------------------------------------------------- launcher
extern "C" void kernel_launch(void* const* d_in, const int* in_sizes, int n_in,
                              void* d_out, int out_size, void* d_ws, size_t ws_size,
                              hipStream_t stream) {
    const float* hid  = (const float*)d_in[0];
    const float* enc  = (const float*)d_in[1];
    const float* mask = (const float*)d_in[2];
    const float* Wq   = (const float*)d_in[3];
    const float* bq   = (const float*)d_in[4];
    const float* Wk   = (const float*)d_in[5];
    const float* bk   = (const float*)d_in[6];
    const float* Wv   = (const float*)d_in[7];
    const float* bv   = (const float*)d_in[8];
    float* out = (float*)d_out;

    char* ws = (char*)d_ws;
    f16* Wtq  = (f16*)(ws + ((size_t)0 << 20));
    f16* Wtk  = (f16*)(ws + ((size_t)2 << 20));
    f16* Wtv  = (f16*)(ws + ((size_t)4 << 20));
    f16* Aall = (f16*)(ws + ((size_t)6 << 20));   // 16 MiB
    f16* Qw   = (f16*)(ws + ((size_t)22 << 20));  // 8 MiB
    f16* Kw   = (f16*)(ws + ((size_t)30 << 20));  // 16 MiB
    f16* Vtw  = (f16*)(ws + ((size_t)46 << 20));  // 16 MiB

    prep_kernel<<<7168, 256, 0, stream>>>(hid, enc, Wq, Wk, Wv, Wtq, Wtk, Wtv, Aall);

    qkv_gemm<<<dim3(64, 8, 3), 256, 0, stream>>>(Aall, Wtq, Wtk, Wtv, bq, bk, bv, Qw, Kw, Vtw);

    attn_kernel<<<dim3(8, 64), 256, 0, stream>>>(Qw, Kw, Vtw, mask, out);
}